// Round 5
// baseline (572.094 us; speedup 1.0000x reference)
//
#include <hip/hip_runtime.h>
#include <math.h>

// Problem constants (from reference): N=2048, IN_SIZE=256, HEADS=4, OUT_SIZE=32
#define GN 2048
#define GIN 256
#define GHEADS 4
#define GOUT 32
#define GNH (GHEADS * GOUT)   // 128 feat columns

typedef float f32x4 __attribute__((ext_vector_type(4)));

// Math reduction (derived from the reference semantics):
//   feat = (h @ W.T).reshape(N, HEADS, OUT)
//   s[n,h] = sum_o feat[n,h,o] * (attn_a[h,o] + attn_a[h,OUT+o])
//   e[n,h] = leaky_relu(2*s[n,h], 0.01)
//   att[n,h,j] = adj[n,j] > 0 ? e[n,h] : -inf   (constant in j!)
//   softmax over HEADS axis -> weights w[n,h] independent of j where adj>0;
//   an all-(-inf) column (adj<=0) -> NaN (faithfully reproduced).
//   out[n,j,o] = adj[n,j] > 0 ? sum_h w[n,h]*feat[n,h,o] : NaN
// So: compute g[n,:] = sum_h w[n,h]*feat[n,h,:] once per row, then do a
// 512 MiB gated broadcast-write. HBM-write-bound (~88 us roofline).
__global__ __launch_bounds__(256) void
DenseGATLayer_90108413870812_kernel(const float* __restrict__ adj,
                                    const float* __restrict__ h,
                                    const float* __restrict__ W,
                                    const float* __restrict__ attn_a,
                                    f32x4* __restrict__ out)
{
    const int n   = blockIdx.x;
    const int tid = threadIdx.x;

    __shared__ float sh_h[GIN];     // h row (1 KiB)
    __shared__ float sh_tmp[GNH];   // w*feat scratch (512 B)
    __shared__ float sh_s[GHEADS];  // per-head scores
    __shared__ float sh_g[GOUT];    // final g row (128 B)

    // ---- load h row into LDS (128 threads x float2) ----
    if (tid < 128) {
        const float2* hr = reinterpret_cast<const float2*>(h + (size_t)n * GIN);
        reinterpret_cast<float2*>(sh_h)[tid] = hr[tid];
    }
    __syncthreads();

    // ---- feat + per-head score (threads 0..127; one thread per feat col) ----
    float feat = 0.f;            // live across the barrier below
    const int head = tid >> 5;   // 0..3 (only meaningful for tid<128)
    if (tid < GNH) {
        const int o = tid & 31;  // 0..31

        const f32x4* Wr = reinterpret_cast<const f32x4*>(W + (size_t)tid * GIN);
        const f32x4* hv = reinterpret_cast<const f32x4*>(sh_h);
        float a0 = 0.f, a1 = 0.f, a2 = 0.f, a3 = 0.f;
        #pragma unroll 8
        for (int k4 = 0; k4 < GIN / 4; ++k4) {
            f32x4 w4 = Wr[k4];
            f32x4 h4 = hv[k4];
            a0 = fmaf(h4.x, w4.x, a0);
            a1 = fmaf(h4.y, w4.y, a1);
            a2 = fmaf(h4.z, w4.z, a2);
            a3 = fmaf(h4.w, w4.w, a3);
        }
        feat = (a0 + a1) + (a2 + a3);

        // s[n,h] = sum_o feat[h,o] * (attn_a[h,o] + attn_a[h,32+o])
        const float aco = attn_a[head * (2 * GOUT) + o] +
                          attn_a[head * (2 * GOUT) + GOUT + o];
        float p = feat * aco;
        // butterfly reduce across the 32-lane head group (masks <=16 stay
        // within each aligned 32-lane half of the wave64)
        #pragma unroll
        for (int m = 16; m >= 1; m >>= 1)
            p += __shfl_xor(p, m, 64);
        if (o == 0) sh_s[head] = p;
    }
    __syncthreads();

    // ---- softmax over 4 heads (redundant per thread), weighted feat ----
    if (tid < GNH) {
        float e[GHEADS];
        float mx = -INFINITY;
        #pragma unroll
        for (int i = 0; i < GHEADS; ++i) {
            const float s2 = 2.f * sh_s[i];
            e[i] = (s2 > 0.f) ? s2 : 0.01f * s2;   // leaky_relu(s+s)
            mx = fmaxf(mx, e[i]);
        }
        float denom = 0.f;
        #pragma unroll
        for (int i = 0; i < GHEADS; ++i) {
            e[i] = expf(e[i] - mx);
            denom += e[i];
        }
        sh_tmp[tid] = (e[head] / denom) * feat;
    }
    __syncthreads();

    if (tid < GOUT) {
        sh_g[tid] = sh_tmp[tid] + sh_tmp[tid + 32] +
                    sh_tmp[tid + 64] + sh_tmp[tid + 96];
    }
    __syncthreads();

    // ---- broadcast write: out[n,j,o] = adj[n,j]>0 ? g[o] : NaN ----
    // Each thread owns quarter q = tid&7 of the 32-float g row (one float4),
    // writes 64 float4s: idx = tid + iter*256, j = idx>>3. 16 B/lane,
    // coalesced (256 threads = 4 KiB contiguous per iter), nontemporal
    // stores (512 MiB output is 2x L3 -- don't pollute caches) and
    // nontemporal adj loads (read exactly once -- keep L2 for W/h).
    const int q = tid & 7;
    const f32x4 gq = reinterpret_cast<const f32x4*>(sh_g)[q];
    const float nanv = __builtin_nanf("");
    const f32x4 nan4 = { nanv, nanv, nanv, nanv };

    const float* __restrict__ arow = adj + (size_t)n * GN;
    f32x4* __restrict__ orow = out + (size_t)n * (GN * (GOUT / 4));

    #pragma unroll 8
    for (int iter = 0; iter < (GN * (GOUT / 4)) / 256; ++iter) {  // 64 iters
        const int idx = tid + iter * 256;
        const int j   = idx >> 3;
        const float av = __builtin_nontemporal_load(arow + j);
        const f32x4 v = (av > 0.f) ? gq : nan4;
        __builtin_nontemporal_store(v, orow + idx);
    }
}

extern "C" void kernel_launch(void* const* d_in, const int* in_sizes, int n_in,
                              void* d_out, int out_size, void* d_ws, size_t ws_size,
                              hipStream_t stream) {
    const float* adj    = (const float*)d_in[0];
    const float* h      = (const float*)d_in[1];
    const float* W      = (const float*)d_in[2];
    const float* attn_a = (const float*)d_in[3];
    f32x4* out = (f32x4*)d_out;

    DenseGATLayer_90108413870812_kernel<<<GN, 256, 0, stream>>>(adj, h, W, attn_a, out);
}

// Round 7
// 545.570 us; speedup vs baseline: 1.0486x; 1.0486x over previous
//
#include <hip/hip_runtime.h>
#include <math.h>

// Problem constants (from reference): N=2048, IN_SIZE=256, HEADS=4, OUT_SIZE=32
#define GN 2048
#define GIN 256
#define GHEADS 4
#define GOUT 32
#define GNH (GHEADS * GOUT)   // 128 feat columns

typedef float f32x4 __attribute__((ext_vector_type(4)));

// Math reduction (derived from the reference semantics):
//   feat = (h @ W.T).reshape(N, HEADS, OUT)
//   s[n,h] = sum_o feat[n,h,o] * (attn_a[h,o] + attn_a[h,OUT+o])
//   e[n,h] = leaky_relu(2*s[n,h], 0.01)
//   att[n,h,j] = adj[n,j] > 0 ? e[n,h] : -inf   (constant in j!)
//   softmax over HEADS -> weights w[n,h] independent of j where adj>0;
//   all-(-inf) column (adj<=0) -> NaN (faithfully reproduced).
//   out[n,j,o] = adj[n,j] > 0 ? sum_h w[n,h]*feat[n,h,o] : NaN
// => per-row 32-float g + 512 MiB gated broadcast-write. HBM-write-bound.
//
// R5 changes (from rocprof): fill kernel proves 6.2 TB/s plain stores on this
// buffer; our NT-store + in-loop NT adj load ran ~2.5 TB/s. Now: adj row
// preloaded to LDS before phase A (latency hidden under feat GEMM), store
// loop gates via LDS broadcast read, plain cached stores.
__global__ __launch_bounds__(256) void
DenseGATLayer_90108413870812_kernel(const float* __restrict__ adj,
                                    const float* __restrict__ h,
                                    const float* __restrict__ W,
                                    const float* __restrict__ attn_a,
                                    f32x4* __restrict__ out)
{
    const int n   = blockIdx.x;
    const int tid = threadIdx.x;

    __shared__ float sh_adj[GN];    // adj row (8 KiB)
    __shared__ float sh_h[GIN];     // h row (1 KiB)
    __shared__ float sh_tmp[GNH];   // w*feat scratch (512 B)
    __shared__ float sh_s[GHEADS];  // per-head scores
    __shared__ float sh_g[GOUT];    // final g row (128 B)

    // ---- issue adj-row + h-row loads (coalesced float4/float2) ----
    const f32x4* arow4 = reinterpret_cast<const f32x4*>(adj + (size_t)n * GN);
    const f32x4 a0 = arow4[tid];
    const f32x4 a1 = arow4[tid + 256];
    float2 h2 = {0.f, 0.f};
    if (tid < 128) {
        const float2* hr = reinterpret_cast<const float2*>(h + (size_t)n * GIN);
        h2 = hr[tid];
    }
    reinterpret_cast<f32x4*>(sh_adj)[tid]       = a0;
    reinterpret_cast<f32x4*>(sh_adj)[tid + 256] = a1;
    if (tid < 128)
        reinterpret_cast<float2*>(sh_h)[tid] = h2;
    __syncthreads();

    // ---- feat + per-head score (threads 0..127; one thread per feat col) ----
    float feat = 0.f;            // live across the barrier below
    const int head = tid >> 5;   // 0..3 (only meaningful for tid<128)
    if (tid < GNH) {
        const int o = tid & 31;  // 0..31

        const f32x4* Wr = reinterpret_cast<const f32x4*>(W + (size_t)tid * GIN);
        const f32x4* hv = reinterpret_cast<const f32x4*>(sh_h);
        float s0 = 0.f, s1 = 0.f, s2 = 0.f, s3 = 0.f;
        #pragma unroll 8
        for (int k4 = 0; k4 < GIN / 4; ++k4) {
            f32x4 w4 = Wr[k4];
            f32x4 h4 = hv[k4];
            s0 = fmaf(h4.x, w4.x, s0);
            s1 = fmaf(h4.y, w4.y, s1);
            s2 = fmaf(h4.z, w4.z, s2);
            s3 = fmaf(h4.w, w4.w, s3);
        }
        feat = (s0 + s1) + (s2 + s3);

        // s[n,h] = sum_o feat[h,o] * (attn_a[h,o] + attn_a[h,32+o])
        const float aco = attn_a[head * (2 * GOUT) + o] +
                          attn_a[head * (2 * GOUT) + GOUT + o];
        float p = feat * aco;
        // butterfly reduce across the 32-lane head group (masks <=16 stay
        // within each aligned 32-lane half of the wave64)
        #pragma unroll
        for (int m = 16; m >= 1; m >>= 1)
            p += __shfl_xor(p, m, 64);
        if (o == 0) sh_s[head] = p;
    }
    __syncthreads();

    // ---- softmax over 4 heads (redundant per thread), weighted feat ----
    if (tid < GNH) {
        float e[GHEADS];
        float mx = -INFINITY;
        #pragma unroll
        for (int i = 0; i < GHEADS; ++i) {
            const float s2 = 2.f * sh_s[i];
            e[i] = (s2 > 0.f) ? s2 : 0.01f * s2;   // leaky_relu(s+s)
            mx = fmaxf(mx, e[i]);
        }
        float denom = 0.f;
        #pragma unroll
        for (int i = 0; i < GHEADS; ++i) {
            e[i] = expf(e[i] - mx);
            denom += e[i];
        }
        sh_tmp[tid] = (e[head] / denom) * feat;
    }
    __syncthreads();

    if (tid < GOUT) {
        sh_g[tid] = sh_tmp[tid] + sh_tmp[tid + 32] +
                    sh_tmp[tid + 64] + sh_tmp[tid + 96];
    }
    __syncthreads();

    // ---- broadcast write: out[n,j,o] = adj[n,j]>0 ? g[o] : NaN ----
    // Thread owns quarter q = tid&7 of the g row (one float4); per iter the
    // block writes 4 KiB contiguous. Gate comes from LDS broadcast read
    // (8 lanes share one address, banks 0..7 -- conflict-free), so the
    // global-store stream has no vmcnt dependency.
    const int q = tid & 7;
    const f32x4 gq = reinterpret_cast<const f32x4*>(sh_g)[q];
    const float nanv = __builtin_nanf("");
    const f32x4 nan4 = { nanv, nanv, nanv, nanv };

    f32x4* __restrict__ orow = out + (size_t)n * (GN * (GOUT / 4));
    const int jbase = tid >> 3;   // 0..31

    #pragma unroll 8
    for (int iter = 0; iter < (GN * (GOUT / 4)) / 256; ++iter) {  // 64 iters
        const float av = sh_adj[jbase + iter * 32];
        const f32x4 v = (av > 0.f) ? gq : nan4;
        orow[tid + iter * 256] = v;
    }
}

extern "C" void kernel_launch(void* const* d_in, const int* in_sizes, int n_in,
                              void* d_out, int out_size, void* d_ws, size_t ws_size,
                              hipStream_t stream) {
    const float* adj    = (const float*)d_in[0];
    const float* h      = (const float*)d_in[1];
    const float* W      = (const float*)d_in[2];
    const float* attn_a = (const float*)d_in[3];
    f32x4* out = (f32x4*)d_out;

    DenseGATLayer_90108413870812_kernel<<<GN, 256, 0, stream>>>(adj, h, W, attn_a, out);
}

// Round 9
// 541.185 us; speedup vs baseline: 1.0571x; 1.0081x over previous
//
#include <hip/hip_runtime.h>
#include <math.h>

// Problem constants (from reference): N=2048, IN_SIZE=256, HEADS=4, OUT_SIZE=32
#define GN 2048
#define GIN 256
#define GHEADS 4
#define GOUT 32
#define GNH (GHEADS * GOUT)   // 128 feat columns

typedef float f32x4 __attribute__((ext_vector_type(4)));

// Math reduction (derived from the reference semantics):
//   feat = (h @ W.T).reshape(N, HEADS, OUT)
//   s[n,h] = sum_o feat[n,h,o] * (attn_a[h,o] + attn_a[h,OUT+o])
//   e[n,h] = leaky_relu(2*s[n,h], 0.01)
//   att[n,h,j] = adj[n,j] > 0 ? e[n,h] : -inf   (constant in j!)
//   softmax over HEADS -> weights w[n,h] independent of j where adj>0;
//   all-(-inf) column (adj<=0) -> NaN (faithfully reproduced).
//   out[n,j,o] = adj[n,j] > 0 ? sum_h w[n,h]*feat[n,h,o] : NaN
// => per-row 32-float g + 512 MiB gated broadcast-write. HBM-write-bound.
//
// R7 state: kernel ~100-115us inferred (dur_us 545 = ~425us harness poison
// fills + restores + kernel). Write roofline 88us. This round: split-K GEMM
// across all 256 threads to shrink the serial prologue (~-8us predicted).
__global__ __launch_bounds__(256) void
DenseGATLayer_90108413870812_kernel(const float* __restrict__ adj,
                                    const float* __restrict__ h,
                                    const float* __restrict__ W,
                                    const float* __restrict__ attn_a,
                                    f32x4* __restrict__ out)
{
    const int n   = blockIdx.x;
    const int tid = threadIdx.x;

    __shared__ float sh_adj[GN];     // adj row (8 KiB)
    __shared__ float sh_h[GIN];      // h row (1 KiB)
    __shared__ float sh_part[256];   // split-K partials (1 KiB)
    __shared__ float sh_tmp[GNH];    // w*feat scratch (512 B)
    __shared__ float sh_s[GHEADS];   // per-head scores
    __shared__ float sh_g[GOUT];     // final g row (128 B)

    // ---- coalesced prefetch: adj row (2x f32x4/thread) + h row ----
    const f32x4* arow4 = reinterpret_cast<const f32x4*>(adj + (size_t)n * GN);
    const f32x4 a0 = arow4[tid];
    const f32x4 a1 = arow4[tid + 256];
    f32x4 hv4 = {0.f, 0.f, 0.f, 0.f};
    if (tid < 64)
        hv4 = reinterpret_cast<const f32x4*>(h + (size_t)n * GIN)[tid];
    reinterpret_cast<f32x4*>(sh_adj)[tid]       = a0;
    reinterpret_cast<f32x4*>(sh_adj)[tid + 256] = a1;
    if (tid < 64)
        reinterpret_cast<f32x4*>(sh_h)[tid] = hv4;
    __syncthreads();

    // ---- split-K GEMM: all 256 threads. thread = (col c, K-half hk) ----
    {
        const int c  = tid & 127;    // feat column 0..127
        const int hk = tid >> 7;     // K-half 0/1 (k in [128*hk, 128*hk+128))
        const f32x4* Wr = reinterpret_cast<const f32x4*>(W + (size_t)c * GIN) + 32 * hk;
        const f32x4* hv = reinterpret_cast<const f32x4*>(sh_h) + 32 * hk;
        float s0 = 0.f, s1 = 0.f, s2 = 0.f, s3 = 0.f;
        #pragma unroll 8
        for (int k4 = 0; k4 < 32; ++k4) {
            f32x4 w4 = Wr[k4];
            f32x4 h4 = hv[k4];
            s0 = fmaf(h4.x, w4.x, s0);
            s1 = fmaf(h4.y, w4.y, s1);
            s2 = fmaf(h4.z, w4.z, s2);
            s3 = fmaf(h4.w, w4.w, s3);
        }
        sh_part[tid] = (s0 + s1) + (s2 + s3);
    }
    __syncthreads();

    // ---- combine halves + per-head score (threads 0..127, col c = tid) ----
    float feat = 0.f;            // live across the barrier below
    const int head = tid >> 5;   // 0..3 (only meaningful for tid<128)
    if (tid < GNH) {
        const int o = tid & 31;  // 0..31
        feat = sh_part[tid] + sh_part[tid + 128];

        // s[n,h] = sum_o feat[h,o] * (attn_a[h,o] + attn_a[h,32+o])
        const float aco = attn_a[head * (2 * GOUT) + o] +
                          attn_a[head * (2 * GOUT) + GOUT + o];
        float p = feat * aco;
        // butterfly reduce across each aligned 32-lane head group
        #pragma unroll
        for (int m = 16; m >= 1; m >>= 1)
            p += __shfl_xor(p, m, 64);
        if (o == 0) sh_s[head] = p;
    }
    __syncthreads();

    // ---- softmax over 4 heads (redundant per thread), weighted feat ----
    if (tid < GNH) {
        float e[GHEADS];
        float mx = -INFINITY;
        #pragma unroll
        for (int i = 0; i < GHEADS; ++i) {
            const float s2 = 2.f * sh_s[i];
            e[i] = (s2 > 0.f) ? s2 : 0.01f * s2;   // leaky_relu(s+s)
            mx = fmaxf(mx, e[i]);
        }
        float denom = 0.f;
        #pragma unroll
        for (int i = 0; i < GHEADS; ++i) {
            e[i] = expf(e[i] - mx);
            denom += e[i];
        }
        sh_tmp[tid] = (e[head] / denom) * feat;
    }
    __syncthreads();

    if (tid < GOUT) {
        sh_g[tid] = sh_tmp[tid] + sh_tmp[tid + 32] +
                    sh_tmp[tid + 64] + sh_tmp[tid + 96];
    }
    __syncthreads();

    // ---- broadcast write: out[n,j,o] = adj[n,j]>0 ? g[o] : NaN ----
    // Thread owns quarter q = tid&7 of the g row (one float4); per iter the
    // block writes 4 KiB contiguous. Gate via LDS broadcast read (8 lanes
    // share an address; each wave touches 8 banks, conflict-free) so the
    // global-store stream has no vmcnt dependency. Plain cached stores
    // (matches the 6.3 TB/s fill-kernel path).
    const int q = tid & 7;
    const f32x4 gq = reinterpret_cast<const f32x4*>(sh_g)[q];
    const float nanv = __builtin_nanf("");
    const f32x4 nan4 = { nanv, nanv, nanv, nanv };

    f32x4* __restrict__ orow = out + (size_t)n * (GN * (GOUT / 4));
    const int jbase = tid >> 3;   // 0..31

    #pragma unroll 8
    for (int iter = 0; iter < (GN * (GOUT / 4)) / 256; ++iter) {  // 64 iters
        const float av = sh_adj[jbase + iter * 32];
        const f32x4 v = (av > 0.f) ? gq : nan4;
        orow[tid + iter * 256] = v;
    }
}

extern "C" void kernel_launch(void* const* d_in, const int* in_sizes, int n_in,
                              void* d_out, int out_size, void* d_ws, size_t ws_size,
                              hipStream_t stream) {
    const float* adj    = (const float*)d_in[0];
    const float* h      = (const float*)d_in[1];
    const float* W      = (const float*)d_in[2];
    const float* attn_a = (const float*)d_in[3];
    f32x4* out = (f32x4*)d_out;

    DenseGATLayer_90108413870812_kernel<<<GN, 256, 0, stream>>>(adj, h, W, attn_a, out);
}

// Round 14
// 539.819 us; speedup vs baseline: 1.0598x; 1.0025x over previous
//
#include <hip/hip_runtime.h>
#include <math.h>

// Problem constants: N=2048, IN_SIZE=256, HEADS=4, OUT_SIZE=32
#define GN 2048
#define GIN 256
#define GHEADS 4
#define GOUT 32
#define GNH (GHEADS * GOUT)   // 128 feat columns

typedef float f32x4 __attribute__((ext_vector_type(4)));

// Math reduction (derived from the reference semantics):
//   feat = (h @ W.T).reshape(N, HEADS, OUT)
//   s[n,h] = sum_o feat[n,h,o] * (attn_a[h,o] + attn_a[h,OUT+o])
//   e[n,h] = leaky_relu(2*s[n,h], 0.01)
//   att[n,h,j] = adj[n,j] > 0 ? e[n,h] : -inf   (constant in j!)
//   softmax over HEADS -> w[n,h] independent of j where adj>0; adj<=0 -> NaN.
//   out[n,j,o] = adj[n,j] > 0 ? g[n,o] : NaN,  g[n,:] = sum_h w[n,h]*feat[n,h,:]
//
// R9: split into K1 (all g rows -> d_ws, W reuse x8) + K2 (pure gated
// streamer). Removes the ~15-20us serial prologue from the store kernel.

// ---- Kernel 1: g[n][o] for all rows. 256 blocks x 256 thr, 8 rows/block ----
__global__ __launch_bounds__(256) void gat_gvec(
    const float* __restrict__ h, const float* __restrict__ W,
    const float* __restrict__ attn_a, float* __restrict__ g)
{
    const int n0  = blockIdx.x * 8;
    const int tid = threadIdx.x;

    __shared__ f32x4 sh_h4[8 * 64];      // 8 h rows (8 KiB)
    __shared__ float sh_s[8][GHEADS];    // scores
    __shared__ float sh_wf[8][GNH];      // w*feat (4 KiB)

    // load 8 h rows (512 f32x4, coalesced, 2 per thread)
    const f32x4* h4 = reinterpret_cast<const f32x4*>(h) + (size_t)n0 * 64;
    sh_h4[tid]       = h4[tid];
    sh_h4[tid + 256] = h4[tid + 256];
    __syncthreads();

    const int c    = tid & 127;    // feat column 0..127
    const int rg   = tid >> 7;     // row group: rows rg*4 .. rg*4+3
    const int head = c >> 5;
    const int o    = c & 31;

    // GEMM: thread = (c, 4 rows); W row read once, reused across 4 rows
    const f32x4* Wr = reinterpret_cast<const f32x4*>(W) + (size_t)c * 64;
    f32x4 ac0 = {0,0,0,0}, ac1 = {0,0,0,0}, ac2 = {0,0,0,0}, ac3 = {0,0,0,0};
    const f32x4* hb = &sh_h4[rg * 4 * 64];
    #pragma unroll 4
    for (int k4 = 0; k4 < 64; ++k4) {
        const f32x4 w4 = Wr[k4];
        ac0 += w4 * hb[k4];            // LDS broadcast reads (same addr/wave)
        ac1 += w4 * hb[64 + k4];
        ac2 += w4 * hb[128 + k4];
        ac3 += w4 * hb[192 + k4];
    }
    float feat0 = (ac0.x + ac0.y) + (ac0.z + ac0.w);
    float feat1 = (ac1.x + ac1.y) + (ac1.z + ac1.w);
    float feat2 = (ac2.x + ac2.y) + (ac2.z + ac2.w);
    float feat3 = (ac3.x + ac3.y) + (ac3.z + ac3.w);

    // per-head scores: butterfly over the aligned 32-lane head group
    const float aco = attn_a[head * (2 * GOUT) + o] +
                      attn_a[head * (2 * GOUT) + GOUT + o];
    float p0 = feat0 * aco, p1 = feat1 * aco, p2 = feat2 * aco, p3 = feat3 * aco;
    #pragma unroll
    for (int m = 16; m >= 1; m >>= 1) {
        p0 += __shfl_xor(p0, m, 64);
        p1 += __shfl_xor(p1, m, 64);
        p2 += __shfl_xor(p2, m, 64);
        p3 += __shfl_xor(p3, m, 64);
    }
    if (o == 0) {
        sh_s[rg * 4 + 0][head] = p0;
        sh_s[rg * 4 + 1][head] = p1;
        sh_s[rg * 4 + 2][head] = p2;
        sh_s[rg * 4 + 3][head] = p3;
    }
    __syncthreads();

    // softmax over 4 heads per row; weighted feat into LDS
    const float ft[4] = {feat0, feat1, feat2, feat3};
    #pragma unroll
    for (int r = 0; r < 4; ++r) {
        const int row = rg * 4 + r;
        float e[GHEADS];
        float mx = -INFINITY;
        #pragma unroll
        for (int i = 0; i < GHEADS; ++i) {
            const float s2 = 2.f * sh_s[row][i];
            e[i] = (s2 > 0.f) ? s2 : 0.01f * s2;   // leaky_relu(s+s)
            mx = fmaxf(mx, e[i]);
        }
        float denom = 0.f;
        #pragma unroll
        for (int i = 0; i < GHEADS; ++i) { e[i] = expf(e[i] - mx); denom += e[i]; }
        sh_wf[row][c] = (e[head] / denom) * ft[r];
    }
    __syncthreads();

    // g write: 256 threads = 8 rows x 32 outputs
    {
        const int row = tid >> 5;
        const int oo  = tid & 31;
        g[(size_t)(n0 + row) * GOUT + oo] =
            sh_wf[row][oo] + sh_wf[row][32 + oo] +
            sh_wf[row][64 + oo] + sh_wf[row][96 + oo];
    }
}

// ---- Kernel 2: pure gated broadcast-write streamer, 2048 blocks ----
__global__ __launch_bounds__(256) void gat_store(
    const float* __restrict__ adj, const float* __restrict__ g,
    f32x4* __restrict__ out)
{
    const int n   = blockIdx.x;
    const int tid = threadIdx.x;

    __shared__ float sh_adj[GN];    // adj row (8 KiB)

    // prefetch adj row (2x f32x4/thread, coalesced) + own g quarter (L2 hit)
    const f32x4* arow4 = reinterpret_cast<const f32x4*>(adj + (size_t)n * GN);
    const f32x4 a0 = arow4[tid];
    const f32x4 a1 = arow4[tid + 256];
    const int q = tid & 7;
    const f32x4 gq = reinterpret_cast<const f32x4*>(g)[n * 8 + q];
    reinterpret_cast<f32x4*>(sh_adj)[tid]       = a0;
    reinterpret_cast<f32x4*>(sh_adj)[tid + 256] = a1;
    __syncthreads();

    const float nanv = __builtin_nanf("");
    const f32x4 nan4 = { nanv, nanv, nanv, nanv };

    f32x4* __restrict__ orow = out + (size_t)n * (GN * (GOUT / 4));
    const int jbase = tid >> 3;   // 0..31

    // Gate via LDS broadcast read (lgkm-only; 8 banks/wave, conflict-free);
    // plain cached stores (the 6.3 TB/s fill-kernel path), 4 KiB/iter/block.
    #pragma unroll 8
    for (int iter = 0; iter < (GN * (GOUT / 4)) / 256; ++iter) {  // 64 iters
        const float av = sh_adj[jbase + iter * 32];
        const f32x4 v = (av > 0.f) ? gq : nan4;
        orow[tid + iter * 256] = v;
    }
}

extern "C" void kernel_launch(void* const* d_in, const int* in_sizes, int n_in,
                              void* d_out, int out_size, void* d_ws, size_t ws_size,
                              hipStream_t stream) {
    const float* adj    = (const float*)d_in[0];
    const float* h      = (const float*)d_in[1];
    const float* W      = (const float*)d_in[2];
    const float* attn_a = (const float*)d_in[3];
    f32x4* out = (f32x4*)d_out;
    float* g   = (float*)d_ws;   // 2048*32 f32 = 256 KiB scratch

    gat_gvec <<<GN / 8, 256, 0, stream>>>(h, W, attn_a, g);
    gat_store<<<GN,     256, 0, stream>>>(adj, g, out);
}